// Round 10
// baseline (38.769 us; speedup 1.0000x reference)
//
#include <hip/hip_runtime.h>

// Problem constants (B=4, N=2048 fixed by the reference setup)
#define BB 4
#define NN 2048
#define NPTS (BB * NN)                          // 8192 points
#define TS 128                                  // n-tile rows per block
#define TT (NN / TS)                            // 16 tiles per batch
#define NTP (TT * (TT + 1) / 2)                 // 136 tri tile pairs (incl diag)
#define MC 64                                   // m-points staged per block
#define MSPL (TS / MC)                          // 2 m-chunks per tile pair
#define MPW (MC / 4)                            // 16 m-points per wave
#define JPB (NTP * MSPL)                        // 272 jobs per batch
#define NJOBS (JPB * BB)                        // 1088 blocks
#define BLK 256                                 // 4 waves
// weight 2 for every surviving (m<n) pair folded into the final scale
#define SCALE (2.0f / ((float)BB * (float)NN * (float)NN))

// d_ws layout: counter @0, partials @256, SoA packed arrays @1MB
#define WS_COUNTER_OFF 0
#define WS_PART_OFF    256
#define WS_PACK_OFF    (1 << 20)
#define WS_NEEDED      (WS_PACK_OFF + (size_t)NPTS * 5 * 16)

typedef float f2 __attribute__((ext_vector_type(2)));

__device__ __forceinline__ f2 ffma(f2 a, f2 b, f2 c) { return __builtin_elementwise_fma(a, b, c); }
__device__ __forceinline__ f2 fmax2(f2 a, f2 b)      { return __builtin_elementwise_max(a, b); }

__device__ __forceinline__ void quat_to_R(float qw, float qx, float qy, float qz, float* R) {
    R[0] = 1.f - 2.f * (qy * qy + qz * qz);
    R[1] = 2.f * (qx * qy - qz * qw);
    R[2] = 2.f * (qx * qz + qy * qw);
    R[3] = 2.f * (qx * qy + qz * qw);
    R[4] = 1.f - 2.f * (qx * qx + qz * qz);
    R[5] = 2.f * (qy * qz - qx * qw);
    R[6] = 2.f * (qx * qz - qy * qw);
    R[7] = 2.f * (qy * qz + qx * qw);
    R[8] = 1.f - 2.f * (qx * qx + qy * qy);
}

// SoA pack: 5 float4 arrays of NPTS entries each.
// A0={x,y,z,sx} A1={sy,sz,vx,vy} A2={vz,R0,R1,R2} A3={R3,R4,R5,R6} A4={R7,R8,0,0}
__global__ __launch_bounds__(256) void pack_kernel(
    const float* __restrict__ xyz, const float* __restrict__ scales,
    const float* __restrict__ rot, const float* __restrict__ vel,
    float4* __restrict__ pk)
{
    const int i = blockIdx.x * 256 + threadIdx.x;
    if (i >= NPTS) return;
    const size_t i3 = 3 * (size_t)i;
    const float4 q = *reinterpret_cast<const float4*>(rot + 4 * (size_t)i);
    float R[9];
    quat_to_R(q.x, q.y, q.z, q.w, R);
    pk[0 * NPTS + i] = make_float4(xyz[i3], xyz[i3 + 1], xyz[i3 + 2], scales[i3]);
    pk[1 * NPTS + i] = make_float4(scales[i3 + 1], scales[i3 + 2], vel[i3], vel[i3 + 1]);
    pk[2 * NPTS + i] = make_float4(vel[i3 + 2], R[0], R[1], R[2]);
    pk[3 * NPTS + i] = make_float4(R[3], R[4], R[5], R[6]);
    pk[4 * NPTS + i] = make_float4(R[7], R[8], 0.f, 0.f);
}

// Lower-triangle (m<n) pair sum, weight 2 in SCALE. PACKED-f32 inner loop:
// each thread's two n-rows {lane, lane+64} ride in the two halves of f2
// vectors, so the backend can select v_pk_fma_f32 / v_pk_mul_f32 (2 fp32
// per VALU instr). Transcendentals stay scalar (2 per f2 op).
// Block = (batch, tri tile-pair, 64-m-chunk); wave w covers m [w*16,w*16+16).
__global__ __launch_bounds__(BLK) void pair_kernel(
    const float4* __restrict__ pk,
    float* __restrict__ partials, unsigned int* __restrict__ counter,
    float* __restrict__ outp)
{
    __shared__ float4 sm[MC][5];
    __shared__ float wsum[4];
    __shared__ int lastflag;

    const int tid  = threadIdx.x;
    const int lane = tid & 63;
    const int w    = tid >> 6;
    const int jid  = blockIdx.x;
    const int b    = jid / JPB;
    const int rem  = jid % JPB;
    const int p    = rem / MSPL;    // triangular tile-pair index
    const int mcch = rem % MSPL;    // m-chunk

    // decode p -> (ti >= tj)
    int ti = 0;
    while ((ti + 1) * (ti + 2) / 2 <= p) ++ti;
    const int tj = p - ti * (ti + 1) / 2;
    const bool diag = (ti == tj);

    const int n_base = ti * TS;
    const int m_blk  = tj * TS + mcch * MC;
    const int gb     = b * NN;

    // ---- stage m-chunk (64 pts x 5 float4) with all 256 threads ----
    {
        int idx = tid;                        // 320 float4 total
        #pragma unroll 2
        for (int itr = 0; itr < 2 && idx < MC * 5; ++itr, idx += 256) {
            const int c = idx >> 6;           // array index 0..4
            const int j = idx & 63;           // m-point
            sm[j][c] = pk[c * NPTS + gb + m_blk + j];
        }
    }

    // ---- own n-rows {lane, lane+64} as f2 state ----
    const int nx = n_base + lane;             // row in .x
    const int ny = nx + 64;                   // row in .y
    f2 px, py, pz, sx, sy, sz, vx, vy, vz;
    f2 Rn[9];
    #pragma unroll
    for (int r = 0; r < 2; ++r) {
        const int gi = gb + (r == 0 ? nx : ny);
        const float4 n0v = pk[0 * NPTS + gi];
        const float4 n1v = pk[1 * NPTS + gi];
        const float4 n2v = pk[2 * NPTS + gi];
        const float4 n3v = pk[3 * NPTS + gi];
        const float4 n4v = pk[4 * NPTS + gi];
        px[r] = n0v.x; py[r] = n0v.y; pz[r] = n0v.z;
        sx[r] = n0v.w; sy[r] = n1v.x; sz[r] = n1v.y;
        vx[r] = n1v.z; vy[r] = n1v.w; vz[r] = n2v.x;
        Rn[0][r] = n2v.y; Rn[1][r] = n2v.z; Rn[2][r] = n2v.w;
        Rn[3][r] = n3v.x; Rn[4][r] = n3v.y; Rn[5][r] = n3v.z;
        Rn[6][r] = n3v.w; Rn[7][r] = n4v.x; Rn[8][r] = n4v.y;
    }

    __syncthreads();

    f2 acc = (f2)(0.f);
    const int jb = w * MPW;     // this wave's m-subrange (uniform)

    auto inner = [&](bool isDiag) {
        #pragma unroll 4
        for (int jj = 0; jj < MPW; ++jj) {
            const int j = jb + jj;
            const int m = m_blk + j;              // uniform
            const float4 c0 = sm[j][0];
            const float4 c1 = sm[j][1];
            const float4 c2 = sm[j][2];
            const float4 c3 = sm[j][3];
            const float4 c4 = sm[j][4];

            const f2 dx = px - c0.x, dy = py - c0.y, dz = pz - c0.z;
            f2 d2 = ffma(dz, dz, (f2)(1e-8f));
            d2 = ffma(dy, dy, d2);
            d2 = ffma(dx, dx, d2);
            f2 rinv;
            rinv[0] = __builtin_amdgcn_rsqf(d2[0]);
            rinv[1] = __builtin_amdgcn_rsqf(d2[1]);

            // r_dir(n,m): (diff^T R_n) scaled by s_m
            const f2 a0 = ffma(dx, Rn[0], ffma(dy, Rn[3], dz * Rn[6])) * c0.w;
            const f2 a1 = ffma(dx, Rn[1], ffma(dy, Rn[4], dz * Rn[7])) * c1.x;
            const f2 a2 = ffma(dx, Rn[2], ffma(dy, Rn[5], dz * Rn[8])) * c1.y;
            const f2 qa2 = ffma(a0, a0, ffma(a1, a1, a2 * a2));
            f2 qa;
            qa[0] = __builtin_amdgcn_sqrtf(qa2[0]);
            qa[1] = __builtin_amdgcn_sqrtf(qa2[1]);

            // r_dir(m,n): (diff^T R_m) scaled by s_n (sign dies in the square)
            const f2 b0 = ffma(dx, (f2)(c2.y), ffma(dy, (f2)(c3.x), dz * c3.w)) * sx;
            const f2 b1 = ffma(dx, (f2)(c2.z), ffma(dy, (f2)(c3.y), dz * c4.x)) * sy;
            const f2 b2 = ffma(dx, (f2)(c2.w), ffma(dy, (f2)(c3.z), dz * c4.y)) * sz;
            const f2 qb2 = ffma(b0, b0, ffma(b1, b1, b2 * b2));
            f2 qb;
            qb[0] = __builtin_amdgcn_sqrtf(qb2[0]);
            qb[1] = __builtin_amdgcn_sqrtf(qb2[1]);

            // overlap = rinv * relu(qa + qb - d2)
            const f2 ww = fmax2(qa + qb - d2, (f2)(0.f));
            const f2 ov = ww * rinv;
            const f2 den = ffma(ov, (f2)(0.1f), (f2)(1.f));
            f2 rc;
            rc[0] = __builtin_amdgcn_rcpf(den[0]);
            rc[1] = __builtin_amdgcn_rcpf(den[1]);

            // v_approach = (v_n - v_m).diff * rinv ; ramp = relu(-v_approach)
            const f2 vdot = ffma(vx - c1.z, dx, ffma(vy - c1.w, dy, (vz - c2.x) * dz));
            const f2 ramp = fmax2(-vdot * rinv, (f2)(0.f));

            // t = ov * (ov*rc + 0.1*ramp)
            f2 t = ov * ffma(ov, rc, ramp * 0.1f);
            if (isDiag) {
                t[0] = (m < nx) ? t[0] : 0.f;
                t[1] = (m < ny) ? t[1] : 0.f;
            }
            acc += t;
        }
    };
    if (diag) inner(true); else inner(false);

    float a = acc[0] + acc[1];

    // ---- block reduction (4 waves) ----
    #pragma unroll
    for (int off = 32; off > 0; off >>= 1)
        a += __shfl_down(a, off, 64);
    if (lane == 0) wsum[w] = a;
    __syncthreads();

    if (tid == 0) {
        partials[jid] = wsum[0] + wsum[1] + wsum[2] + wsum[3];
        __threadfence();                               // release
        const unsigned int done = atomicAdd(counter, 1u);
        lastflag = (done == (unsigned int)(NJOBS - 1));
    }
    __syncthreads();

    if (lastflag) {
        __threadfence();                               // acquire
        const float4* p4 = reinterpret_cast<const float4*>(partials);
        float s = 0.f;
        for (int i = tid; i < NJOBS / 4; i += BLK) {
            const float4 v = p4[i];
            s += v.x + v.y + v.z + v.w;
        }
        #pragma unroll
        for (int off = 32; off > 0; off >>= 1)
            s += __shfl_down(s, off, 64);
        if (lane == 0) wsum[w] = s;
        __syncthreads();
        if (tid == 0) outp[0] = (wsum[0] + wsum[1] + wsum[2] + wsum[3]) * SCALE;
    }
}

// Safety fallback (tiny workspace): one thread per n-row, loops m<n, atomic.
__global__ __launch_bounds__(256) void naive_kernel(
    const float* __restrict__ xyz, const float* __restrict__ scales,
    const float* __restrict__ rot, const float* __restrict__ vel,
    float* __restrict__ outp)
{
    const int g = blockIdx.x * 256 + threadIdx.x;   // 8192 threads
    const int b = g / NN, n = g % NN;
    const size_t i3 = ((size_t)b * NN + n) * 3;
    const float4 qn = *reinterpret_cast<const float4*>(rot + ((size_t)b * NN + n) * 4);
    float Rn[9];
    quat_to_R(qn.x, qn.y, qn.z, qn.w, Rn);
    const float px = xyz[i3], py = xyz[i3+1], pz = xyz[i3+2];
    const float sx = scales[i3], sy = scales[i3+1], sz = scales[i3+2];
    const float vx = vel[i3], vy = vel[i3+1], vz = vel[i3+2];
    float acc = 0.f;
    for (int m = 0; m < n; ++m) {
        const size_t j3 = ((size_t)b * NN + m) * 3;
        const float4 qm = *reinterpret_cast<const float4*>(rot + ((size_t)b * NN + m) * 4);
        float Rm[9];
        quat_to_R(qm.x, qm.y, qm.z, qm.w, Rm);
        const float dx = px - xyz[j3], dy = py - xyz[j3+1], dz = pz - xyz[j3+2];
        const float d2 = fmaf(dx, dx, fmaf(dy, dy, fmaf(dz, dz, 1e-8f)));
        const float rinv = __builtin_amdgcn_rsqf(d2);
        const float a0 = fmaf(dx, Rn[0], fmaf(dy, Rn[3], dz*Rn[6])) * scales[j3];
        const float a1 = fmaf(dx, Rn[1], fmaf(dy, Rn[4], dz*Rn[7])) * scales[j3+1];
        const float a2 = fmaf(dx, Rn[2], fmaf(dy, Rn[5], dz*Rn[8])) * scales[j3+2];
        const float qa = __builtin_amdgcn_sqrtf(fmaf(a0,a0,fmaf(a1,a1,a2*a2)));
        const float b0 = fmaf(dx, Rm[0], fmaf(dy, Rm[3], dz*Rm[6])) * sx;
        const float b1 = fmaf(dx, Rm[1], fmaf(dy, Rm[4], dz*Rm[7])) * sy;
        const float b2 = fmaf(dx, Rm[2], fmaf(dy, Rm[5], dz*Rm[8])) * sz;
        const float qb = __builtin_amdgcn_sqrtf(fmaf(b0,b0,fmaf(b1,b1,b2*b2)));
        const float ww = fmaxf(qa + qb - d2, 0.f);
        const float ov = ww * rinv;
        const float rc = __builtin_amdgcn_rcpf(fmaf(0.1f, ov, 1.f));
        const float vdot = fmaf(vx - vel[j3], dx, fmaf(vy - vel[j3+1], dy, (vz - vel[j3+2]) * dz));
        const float ramp = fmaxf(-vdot * rinv, 0.f);
        acc += ov * fmaf(ov, rc, 0.1f * ramp);
    }
    #pragma unroll
    for (int off = 32; off > 0; off >>= 1)
        acc += __shfl_down(acc, off, 64);
    if ((threadIdx.x & 63) == 0) atomicAdd(outp, acc * SCALE);
}

extern "C" void kernel_launch(void* const* d_in, const int* in_sizes, int n_in,
                              void* d_out, int out_size, void* d_ws, size_t ws_size,
                              hipStream_t stream)
{
    const float* xyz    = (const float*)d_in[0];
    const float* scales = (const float*)d_in[1];
    const float* rot    = (const float*)d_in[2];
    const float* vel    = (const float*)d_in[3];
    float* out = (float*)d_out;

    if (ws_size >= WS_NEEDED) {
        unsigned int* counter = (unsigned int*)((char*)d_ws + WS_COUNTER_OFF);
        float* partials       = (float*)((char*)d_ws + WS_PART_OFF);
        float4* pk            = (float4*)((char*)d_ws + WS_PACK_OFF);
        hipMemsetAsync(counter, 0, sizeof(unsigned int), stream);   // graph-safe
        pack_kernel<<<(NPTS + 255) / 256, 256, 0, stream>>>(xyz, scales, rot, vel, pk);
        pair_kernel<<<NJOBS, BLK, 0, stream>>>(pk, partials, counter, out);
    } else {
        hipMemsetAsync(d_out, 0, sizeof(float), stream);
        naive_kernel<<<NPTS / 256, 256, 0, stream>>>(xyz, scales, rot, vel, out);
    }
}

// Round 11
// 36.561 us; speedup vs baseline: 1.0604x; 1.0604x over previous
//
#include <hip/hip_runtime.h>

// Problem constants (B=4, N=2048 fixed by the reference setup)
#define BB 4
#define NN 2048
#define NPTS (BB * NN)                          // 8192 points
#define RGR 256                                 // rows per group (= block threads)
#define NG (NN / RGR)                           // 8 row-groups per batch
#define MW 64                                   // m-window per block
// group g (0..7) needs m < (g+1)*RGR -> 4*(g+1) windows of 64
// cum[g] = 2*g*(g+1); blocks per batch = 144
#define JPB 144
#define NJOBS (JPB * BB)                        // 576 blocks
#define BLK 256                                 // 4 waves
// weight 2 for every surviving (m<n) pair folded into the final scale
#define SCALE (2.0f / ((float)BB * (float)NN * (float)NN))

// d_ws layout: counter @0, partials @256, SoA packed arrays @1MB
#define WS_COUNTER_OFF 0
#define WS_PART_OFF    256
#define WS_PACK_OFF    (1 << 20)
#define WS_NEEDED      (WS_PACK_OFF + (size_t)NPTS * 5 * 16)

__device__ __forceinline__ void quat_to_R(float qw, float qx, float qy, float qz, float* R) {
    R[0] = 1.f - 2.f * (qy * qy + qz * qz);
    R[1] = 2.f * (qx * qy - qz * qw);
    R[2] = 2.f * (qx * qz + qy * qw);
    R[3] = 2.f * (qx * qy + qz * qw);
    R[4] = 1.f - 2.f * (qx * qx + qz * qz);
    R[5] = 2.f * (qy * qz - qx * qw);
    R[6] = 2.f * (qx * qz - qy * qw);
    R[7] = 2.f * (qy * qz + qx * qw);
    R[8] = 1.f - 2.f * (qx * qx + qy * qy);
}

// SoA pack: 5 float4 arrays of NPTS entries each.
// A0={x,y,z,sx} A1={sy,sz,vx,vy} A2={vz,R0,R1,R2} A3={R3,R4,R5,R6} A4={R7,R8,0,0}
__global__ __launch_bounds__(256) void pack_kernel(
    const float* __restrict__ xyz, const float* __restrict__ scales,
    const float* __restrict__ rot, const float* __restrict__ vel,
    float4* __restrict__ pk)
{
    const int i = blockIdx.x * 256 + threadIdx.x;
    if (i >= NPTS) return;
    const size_t i3 = 3 * (size_t)i;
    const float4 q = *reinterpret_cast<const float4*>(rot + 4 * (size_t)i);
    float R[9];
    quat_to_R(q.x, q.y, q.z, q.w, R);
    pk[0 * NPTS + i] = make_float4(xyz[i3], xyz[i3 + 1], xyz[i3 + 2], scales[i3]);
    pk[1 * NPTS + i] = make_float4(scales[i3 + 1], scales[i3 + 2], vel[i3], vel[i3 + 1]);
    pk[2 * NPTS + i] = make_float4(vel[i3 + 2], R[0], R[1], R[2]);
    pk[3 * NPTS + i] = make_float4(R[3], R[4], R[5], R[6]);
    pk[4 * NPTS + i] = make_float4(R[7], R[8], 0.f, 0.f);
}

// Lower-triangle (m<n) pair sum, weight 2 in SCALE.
// Ragged grid: block = (batch, row-group g, m-window s). Group g covers rows
// [g*256,(g+1)*256); its m-range [0,(g+1)*256) is split into 4*(g+1) windows
// of 64. One code path; per-pair m<n predicate (v_cndmask). Each thread owns
// ONE row (= tid); 64 m staged once to LDS ([5][64] SoA, uniform broadcast
// reads); one long 64-iteration loop, unroll 4.
__global__ __launch_bounds__(BLK) void pair_kernel(
    const float4* __restrict__ pk,
    float* __restrict__ partials, unsigned int* __restrict__ counter,
    float* __restrict__ outp)
{
    __shared__ float4 sm[5][MW];
    __shared__ float wsum[4];
    __shared__ int lastflag;

    const int tid = threadIdx.x;
    const int jid = blockIdx.x;
    const int b   = jid / JPB;
    const int r   = jid % JPB;

    // find group g: cum[g] = 2g(g+1) <= r < cum[g+1]
    int g = 0;
    #pragma unroll
    for (int gg = 1; gg < NG; ++gg)
        if (r >= 2 * gg * (gg + 1)) g = gg;
    const int s  = r - 2 * g * (g + 1);   // m-window within group
    const int m0 = s * MW;                // absolute m base (within batch)
    const int n  = g * RGR + tid;         // this thread's row
    const int gb = b * NN;

    // ---- stage 64 m-points (5 arrays x 64 float4 = 320), [c][pt] layout ----
    {
        int e = tid;
        #pragma unroll 2
        for (int it = 0; it < 2 && e < 5 * MW; ++it, e += BLK) {
            const int c  = e >> 6;        // array 0..4
            const int pt = e & 63;        // m-point
            sm[c][pt] = pk[c * NPTS + gb + m0 + pt];
        }
    }

    // ---- own n-row (5 coalesced float4) ----
    const int gi = gb + n;
    const float4 n0v = pk[0 * NPTS + gi];
    const float4 n1v = pk[1 * NPTS + gi];
    const float4 n2v = pk[2 * NPTS + gi];
    const float4 n3v = pk[3 * NPTS + gi];
    const float4 n4v = pk[4 * NPTS + gi];
    const float px = n0v.x, py = n0v.y, pz = n0v.z;
    const float sx = n0v.w, sy = n1v.x, sz = n1v.y;
    const float vx = n1v.z, vy = n1v.w, vz = n2v.x;
    const float Rn0 = n2v.y, Rn1 = n2v.z, Rn2 = n2v.w;
    const float Rn3 = n3v.x, Rn4 = n3v.y, Rn5 = n3v.z;
    const float Rn6 = n3v.w, Rn7 = n4v.x, Rn8 = n4v.y;

    __syncthreads();

    float acc = 0.f;

    #pragma unroll 4
    for (int j = 0; j < MW; ++j) {
        const float4 c0 = sm[0][j];
        const float4 c1 = sm[1][j];
        const float4 c2 = sm[2][j];
        const float4 c3 = sm[3][j];
        const float4 c4 = sm[4][j];
        const float dx = px - c0.x, dy = py - c0.y, dz = pz - c0.z;
        const float d2 = fmaf(dx, dx, fmaf(dy, dy, fmaf(dz, dz, 1e-8f)));
        const float rinv = __builtin_amdgcn_rsqf(d2);
        // r_dir(n,m): (diff^T R_n) scaled by s_m
        const float a0 = fmaf(dx, Rn0, fmaf(dy, Rn3, dz * Rn6)) * c0.w;
        const float a1 = fmaf(dx, Rn1, fmaf(dy, Rn4, dz * Rn7)) * c1.x;
        const float a2 = fmaf(dx, Rn2, fmaf(dy, Rn5, dz * Rn8)) * c1.y;
        const float qa = __builtin_amdgcn_sqrtf(fmaf(a0, a0, fmaf(a1, a1, a2 * a2)));
        // r_dir(m,n): (diff^T R_m) scaled by s_n (sign dies in the square)
        const float b0 = fmaf(dx, c2.y, fmaf(dy, c3.x, dz * c3.w)) * sx;
        const float b1 = fmaf(dx, c2.z, fmaf(dy, c3.y, dz * c4.x)) * sy;
        const float b2 = fmaf(dx, c2.w, fmaf(dy, c3.z, dz * c4.y)) * sz;
        const float qb = __builtin_amdgcn_sqrtf(fmaf(b0, b0, fmaf(b1, b1, b2 * b2)));
        // overlap = rinv * relu(qa + qb - d2)
        const float ww = fmaxf(qa + qb - d2, 0.f);
        const float ov = ww * rinv;
        const float rc = __builtin_amdgcn_rcpf(fmaf(0.1f, ov, 1.f));
        // v_approach = (v_n - v_m).diff * rinv ; ramp = relu(-v_approach)
        const float vdot = fmaf(vx - c1.z, dx, fmaf(vy - c1.w, dy, (vz - c2.x) * dz));
        const float ramp = fmaxf(-vdot * rinv, 0.f);
        // t = ov * (ov*rc + 0.1*ramp); keep only m < n (strict lower triangle)
        const float t = ov * fmaf(ov, rc, 0.1f * ramp);
        acc += (m0 + j < n) ? t : 0.f;
    }

    // ---- block reduction (4 waves) ----
    #pragma unroll
    for (int off = 32; off > 0; off >>= 1)
        acc += __shfl_down(acc, off, 64);
    if ((tid & 63) == 0) wsum[tid >> 6] = acc;
    __syncthreads();

    if (tid == 0) {
        partials[jid] = wsum[0] + wsum[1] + wsum[2] + wsum[3];
        __threadfence();                               // release
        const unsigned int done = atomicAdd(counter, 1u);
        lastflag = (done == (unsigned int)(NJOBS - 1));
    }
    __syncthreads();

    if (lastflag) {
        __threadfence();                               // acquire
        const float4* p4 = reinterpret_cast<const float4*>(partials);
        float s2 = 0.f;
        for (int i = tid; i < NJOBS / 4; i += BLK) {
            const float4 v = p4[i];
            s2 += v.x + v.y + v.z + v.w;
        }
        #pragma unroll
        for (int off = 32; off > 0; off >>= 1)
            s2 += __shfl_down(s2, off, 64);
        if ((tid & 63) == 0) wsum[tid >> 6] = s2;
        __syncthreads();
        if (tid == 0) outp[0] = (wsum[0] + wsum[1] + wsum[2] + wsum[3]) * SCALE;
    }
}

// Safety fallback (tiny workspace): one thread per n-row, loops m<n, atomic.
__global__ __launch_bounds__(256) void naive_kernel(
    const float* __restrict__ xyz, const float* __restrict__ scales,
    const float* __restrict__ rot, const float* __restrict__ vel,
    float* __restrict__ outp)
{
    const int gth = blockIdx.x * 256 + threadIdx.x;   // 8192 threads
    const int b = gth / NN, n = gth % NN;
    const size_t i3 = ((size_t)b * NN + n) * 3;
    const float4 qn = *reinterpret_cast<const float4*>(rot + ((size_t)b * NN + n) * 4);
    float Rn[9];
    quat_to_R(qn.x, qn.y, qn.z, qn.w, Rn);
    const float px = xyz[i3], py = xyz[i3+1], pz = xyz[i3+2];
    const float sx = scales[i3], sy = scales[i3+1], sz = scales[i3+2];
    const float vx = vel[i3], vy = vel[i3+1], vz = vel[i3+2];
    float acc = 0.f;
    for (int m = 0; m < n; ++m) {
        const size_t j3 = ((size_t)b * NN + m) * 3;
        const float4 qm = *reinterpret_cast<const float4*>(rot + ((size_t)b * NN + m) * 4);
        float Rm[9];
        quat_to_R(qm.x, qm.y, qm.z, qm.w, Rm);
        const float dx = px - xyz[j3], dy = py - xyz[j3+1], dz = pz - xyz[j3+2];
        const float d2 = fmaf(dx, dx, fmaf(dy, dy, fmaf(dz, dz, 1e-8f)));
        const float rinv = __builtin_amdgcn_rsqf(d2);
        const float a0 = fmaf(dx, Rn[0], fmaf(dy, Rn[3], dz*Rn[6])) * scales[j3];
        const float a1 = fmaf(dx, Rn[1], fmaf(dy, Rn[4], dz*Rn[7])) * scales[j3+1];
        const float a2 = fmaf(dx, Rn[2], fmaf(dy, Rn[5], dz*Rn[8])) * scales[j3+2];
        const float qa = __builtin_amdgcn_sqrtf(fmaf(a0,a0,fmaf(a1,a1,a2*a2)));
        const float b0 = fmaf(dx, Rm[0], fmaf(dy, Rm[3], dz*Rm[6])) * sx;
        const float b1 = fmaf(dx, Rm[1], fmaf(dy, Rm[4], dz*Rm[7])) * sy;
        const float b2 = fmaf(dx, Rm[2], fmaf(dy, Rm[5], dz*Rm[8])) * sz;
        const float qb = __builtin_amdgcn_sqrtf(fmaf(b0,b0,fmaf(b1,b1,b2*b2)));
        const float ww = fmaxf(qa + qb - d2, 0.f);
        const float ov = ww * rinv;
        const float rc = __builtin_amdgcn_rcpf(fmaf(0.1f, ov, 1.f));
        const float vdot = fmaf(vx - vel[j3], dx, fmaf(vy - vel[j3+1], dy, (vz - vel[j3+2]) * dz));
        const float ramp = fmaxf(-vdot * rinv, 0.f);
        acc += ov * fmaf(ov, rc, 0.1f * ramp);
    }
    #pragma unroll
    for (int off = 32; off > 0; off >>= 1)
        acc += __shfl_down(acc, off, 64);
    if ((threadIdx.x & 63) == 0) atomicAdd(outp, acc * SCALE);
}

extern "C" void kernel_launch(void* const* d_in, const int* in_sizes, int n_in,
                              void* d_out, int out_size, void* d_ws, size_t ws_size,
                              hipStream_t stream)
{
    const float* xyz    = (const float*)d_in[0];
    const float* scales = (const float*)d_in[1];
    const float* rot    = (const float*)d_in[2];
    const float* vel    = (const float*)d_in[3];
    float* out = (float*)d_out;

    if (ws_size >= WS_NEEDED) {
        unsigned int* counter = (unsigned int*)((char*)d_ws + WS_COUNTER_OFF);
        float* partials       = (float*)((char*)d_ws + WS_PART_OFF);
        float4* pk            = (float4*)((char*)d_ws + WS_PACK_OFF);
        hipMemsetAsync(counter, 0, sizeof(unsigned int), stream);   // graph-safe
        pack_kernel<<<(NPTS + 255) / 256, 256, 0, stream>>>(xyz, scales, rot, vel, pk);
        pair_kernel<<<NJOBS, BLK, 0, stream>>>(pk, partials, counter, out);
    } else {
        hipMemsetAsync(d_out, 0, sizeof(float), stream);
        naive_kernel<<<NPTS / 256, 256, 0, stream>>>(xyz, scales, rot, vel, out);
    }
}